// Round 7
// baseline (256.753 us; speedup 1.0000x reference)
//
#include <hip/hip_runtime.h>

// out[b,j,hw] = exp( sum_i log(relu(x[b,i,hw])+0.1) * E[i,j] ) + bias[j]
// x: (B=32, NC=64, H=128, W=128) fp32.
//
// R9. R8 post-mortem: traffic clean (spills fixed) but 90us unchanged --
// VGPR_Count=88 proves the scheduler sank the prefetch loads (live set of a
// real 2-deep pipeline ~140 regs); we re-measured R6. Across all clean runs
// occupancy tracks GRID SIZE, not structure: 1024 blocks->17-19%, 2048->43%,
// 8192->70%. At ~5 waves/CU, in-flight bytes (16 loads x 256B x 5.3 waves /
// ~375ns) cap BW at ~2.9 TB/s -- exactly the measured 2.27. Fix = TLP, the
// lever the compiler can't delete:
//  - 8192 blocks, ONE 64-point tile per block (no grid-stride loop, no
//    software pipeline). Per-block E-frag prologue is L1/L2-resident and
//    absorbed by TLP.
//  - NON-TEMPORAL stores for out: the 134MB out stream was evicting x from
//    L3 (FETCH=66MB = half of x). nt keeps x L3-resident -> FETCH ~10-30MB,
//    total HBM ~150MB. (x loads stay temporal: they WANT L3.)
// Numerics identical to R8 (passed, absmax 0.015625): E-hi only (E entries
// bf16-exact here), lx hi/lo split kept.
// Success signals: Occupancy 50-70%, FETCH <30MB, dur 35-55us, VGPR ~95.
// Failure reads: occ up + dur flat => 64B-segment pattern ceiling -> go
// point-major loads; FETCH flat => nt ignored (neutral).
#define NCH 64
#define HWSZ 16384
#define NPOINTS (32 * HWSZ)      // 524288
#define NTILES (NPOINTS / 64)    // 8192 blocks: 1 tile = 4 waves x 16 pts

typedef __attribute__((ext_vector_type(8))) short bf16x8;  // 8 bf16, 4 VGPRs
typedef __attribute__((ext_vector_type(4))) float f32x4;

union fragU { bf16x8 v; unsigned int u[4]; };

static __device__ __forceinline__ unsigned int fbits(float f) {
    return __float_as_uint(f);
}
static __device__ __forceinline__ float bf16_up_bits(unsigned int b) {
    return __uint_as_float(b & 0xFFFF0000u);
}

__global__ __launch_bounds__(256, 2) void fused_log_einsum_exp(
    const float* __restrict__ x,
    const float* __restrict__ E,     // (64,64) row-major: E[i*64+j]
    const float* __restrict__ bias,  // (64)
    float* __restrict__ out)
{
    const int lane = threadIdx.x & 63;
    const int wv   = threadIdx.x >> 6;   // wave 0..3 within block
    const int lg   = lane >> 4;          // k-group 0..3
    const int ln   = lane & 15;          // row/col-in-fragment 0..15

    // ---- This wave's 16-point slab (tiles never cross a batch boundary).
    const int p0 = blockIdx.x * 64 + wv * 16;
    const size_t base = (size_t)(p0 & ~(HWSZ - 1)) * NCH   // b * 64 * HWSZ
                      + (size_t)(p0 & (HWSZ - 1)) + ln;    // + hw + point

    // ---- Issue the 16 x-gathers FIRST (HBM latency under the prologue).
    // channel i = (e>>3)*32 + lg*8 + (e&7); per instr 4 x 64B segments,
    // sibling waves complete each 128B line.
    float xr[16];
    #pragma unroll
    for (int e = 0; e < 16; ++e)
        xr[e] = x[base + (size_t)((e >> 3) * 32 + lg * 8 + (e & 7)) * HWSZ];

    // ---- A-frags: E^T hi-part (E entries bf16-exact here; see header).
    // A: lane l holds A[row=j=l&15][k=i=(l>>4)*8+e]. L1/L2-resident loads.
    bf16x8 ah[4][2];
    #pragma unroll
    for (int m = 0; m < 4; ++m) {
        #pragma unroll
        for (int kk = 0; kk < 2; ++kk) {
            fragU h;
            #pragma unroll
            for (int w = 0; w < 4; ++w) {
                const int i0 = kk * 32 + lg * 8 + 2 * w;
                const int j  = m * 16 + ln;
                h.u[w] = (fbits(E[(i0 + 1) * NCH + j]) & 0xFFFF0000u)
                       | (fbits(E[i0 * NCH + j]) >> 16);
            }
            ah[m][kk] = h.v;
        }
    }

    // bias for the 16 j's this lane stores: j = m*16 + lg*4 + r
    float bv[4][4];
    #pragma unroll
    for (int m = 0; m < 4; ++m)
        #pragma unroll
        for (int r = 0; r < 4; ++r)
            bv[m][r] = bias[m * 16 + lg * 4 + r];

    // ---- log + hi/lo bf16 split (u32 bit-ops), B-frags in-register.
    // B: lane l holds B[k=(l>>4)*8+e][col=point=l&15].
    bf16x8 bh[2], bl[2];
    #pragma unroll
    for (int kk = 0; kk < 2; ++kk) {
        fragU h_, l_;
        #pragma unroll
        for (int w = 0; w < 4; ++w) {
            const float lx0 = __logf(fmaxf(xr[kk * 8 + 2 * w],     0.0f) + 0.1f);
            const float lx1 = __logf(fmaxf(xr[kk * 8 + 2 * w + 1], 0.0f) + 0.1f);
            h_.u[w] = (fbits(lx1) & 0xFFFF0000u) | (fbits(lx0) >> 16);
            const float lo0 = lx0 - bf16_up_bits(fbits(lx0));
            const float lo1 = lx1 - bf16_up_bits(fbits(lx1));
            l_.u[w] = (fbits(lo1) & 0xFFFF0000u) | (fbits(lo0) >> 16);
        }
        bh[kk] = h_.v; bl[kk] = l_.v;
    }

    // ---- 16 MFMAs (4 j-tiles x 2 k-steps x {E*lx_hi, E*lx_lo}) + epilogue.
    // D: lane l, reg r -> D[row=j=(l>>4)*4+r][col=point=l&15].
    #pragma unroll
    for (int m = 0; m < 4; ++m) {
        f32x4 acc = {0.f, 0.f, 0.f, 0.f};
        #pragma unroll
        for (int kk = 0; kk < 2; ++kk) {
            acc = __builtin_amdgcn_mfma_f32_16x16x32_bf16(ah[m][kk], bh[kk], acc, 0, 0, 0);
            acc = __builtin_amdgcn_mfma_f32_16x16x32_bf16(ah[m][kk], bl[kk], acc, 0, 0, 0);
        }
        #pragma unroll
        for (int r = 0; r < 4; ++r) {
            const int j = m * 16 + lg * 4 + r;
            // out is write-once, never re-read: non-temporal keeps x in L3.
            __builtin_nontemporal_store(__expf(acc[r]) + bv[m][r],
                                        &out[base + (size_t)j * HWSZ]);
        }
    }
}

extern "C" void kernel_launch(void* const* d_in, const int* in_sizes, int n_in,
                              void* d_out, int out_size, void* d_ws, size_t ws_size,
                              hipStream_t stream) {
    const float* x    = (const float*)d_in[0];
    const float* E    = (const float*)d_in[1];   // (64,64,1,1) -> [i*64+j]
    const float* bias = (const float*)d_in[2];   // (64,1,1)
    float* out = (float*)d_out;

    dim3 grid(NTILES), block(256);
    hipLaunchKernelGGL(fused_log_einsum_exp, grid, block, 0, stream,
                       x, E, bias, out);
}

// Round 8
// 242.641 us; speedup vs baseline: 1.0582x; 1.0582x over previous
//
#include <hip/hip_runtime.h>

// out[b,j,hw] = exp( sum_i log(relu(x[b,i,hw])+0.1) * E[i,j] ) + bias[j]
// x: (B=32, NC=64, H=128, W=128) fp32.
//
// R10. Evidence: R0/R2/R6/R8/R9 (5 structures, occ 17%..70%) ALL cap at
// 2.0-2.4 TB/s effective with no pipe >50%. R8 proved the compiler sinks
// register-prefetch loads to uses; R9 proved occupancy doesn't fix it.
// Diagnosis: per-wave load->use serialization the scheduler keeps
// reintroducing. Fix: global_load_lds staging -- a side-effect instruction
// the compiler can NOT sink -- in a double-buffered 2-barrier loop with
// COUNTED vmcnt (T3-lite / m97 structure):
//   tile = 128 pts x 64 ch fp32 = 32KB, dbuf = 64KB LDS -> 2 blocks/CU
//   stage: width-16, 8 instrs/wave/tile, XOR-pre-swizzled global source
//          (G21: linear dest + inv-swz source + swz read) so compute-phase
//          ds_reads are 2-way bank-aliased = free (m136)
//   vmcnt: steady 16 (= 8 stores + 8 next-stage younger than awaited stage,
//          in-order retirement), 8 on first/last iter. NEVER 0.
//   compute: operand-SWAPPED MFMA: A=lx (row=pt), B=E (col=j) -> D[pt][j]
//          => lane holds 4 consecutive pts => dwordx4 stores (8/wave/tile).
//          E hi-only (entries bf16-exact); lx split hi/lo (2 MFMA/frag).
//          k-mapping errors cancel (A,B built with same k convention);
//          D row/col is m89-verified.
// Success: hbm 4-5.5 TB/s, dur 40-55us, WRITE ~134MB (nt reverted), LDS
// 65536, bank-conflict ~0, absmax 0.015625. Failure reads: absmax blown
// -> transpose A-frag build; BW still ~2.3 -> machine-level cap, probe it.
#define NCH 64
#define HWSZ 16384
#define NPOINTS (32 * HWSZ)      // 524288
#define TPTS 128                 // points per tile (128 | HWSZ: no b-cross)
#define NTILES (NPOINTS / TPTS)  // 4096
#define NBLOCKS 1024
#define TPB 4                    // tiles per block (grid-strided)

typedef __attribute__((ext_vector_type(8))) short bf16x8;  // 8 bf16, 4 VGPRs
typedef __attribute__((ext_vector_type(4))) float f32x4;

union fragU { bf16x8 v; unsigned int u[4]; };

static __device__ __forceinline__ unsigned int fbits(float f) {
    return __float_as_uint(f);
}
static __device__ __forceinline__ float bfup(unsigned int b) {
    return __uint_as_float(b & 0xFFFF0000u);
}

__global__ __launch_bounds__(256, 2) void fused_log_einsum_exp(
    const float* __restrict__ x,
    const float* __restrict__ E,     // (64,64) row-major: E[i*64+j]
    const float* __restrict__ bias,  // (64)
    float* __restrict__ out)
{
    __shared__ float lx[2][NCH][TPTS];   // raw x, dbuf: 2*64*128*4 = 64KB

    const int lane = threadIdx.x & 63;
    const int wv   = threadIdx.x >> 6;   // wave 0..3
    const int lg   = lane >> 4;          // 0..3
    const int ln   = lane & 15;          // 0..15

    // ---- B-frags: E straight row-major (k=i, col=j), hi-only. bE[m][kk].
    // B: lane l holds B[k=(l>>4)*8+e][col=l&15]; same k-convention as A.
    bf16x8 bE[4][2];
    #pragma unroll
    for (int m = 0; m < 4; ++m) {
        #pragma unroll
        for (int kk = 0; kk < 2; ++kk) {
            fragU h;
            #pragma unroll
            for (int w = 0; w < 4; ++w) {
                const int i0 = kk * 32 + lg * 8 + 2 * w;
                const int j  = m * 16 + ln;
                h.u[w] = (fbits(E[(i0 + 1) * NCH + j]) & 0xFFFF0000u)
                       | (fbits(E[i0 * NCH + j]) >> 16);
            }
            bE[m][kk] = h.v;
        }
    }

    // bias: this lane stores j = m*16 + ln (same j for all 4 pts in a frag)
    float bj[4];
    #pragma unroll
    for (int m = 0; m < 4; ++m) bj[m] = bias[m * 16 + ln];

// float-index base of tile T (pt0 = T*128): b*NCH*HWSZ + hw0
#define TILE_PB(T) ((size_t)(((T) * TPTS) & ~(HWSZ - 1)) * NCH \
                  + (size_t)(((T) * TPTS) & (HWSZ - 1)))

// Stage tile T into lx[BSEL]: wave wv covers planes [wv*16, wv*16+16).
// Instr n: planes (wv*16+2n, +1); lanes 0-31 -> first plane (512B), 32-63 ->
// second. Dest linear (lane*16B); source pre-XOR-swizzled: word (l&31)*4 ^ sw,
// sw = ((plane>>3)&1)<<4  => read side applies same XOR => banks 2-way. G21 ok.
#define STAGE(BSEL, T) do {                                                    \
    const size_t pb_ = TILE_PB(T);                                             \
    _Pragma("unroll")                                                          \
    for (int n_ = 0; n_ < 8; ++n_) {                                           \
        const int row_   = wv * 16 + 2 * n_;                                   \
        const int plane_ = row_ + (lane >> 5);                                 \
        const int sw_    = ((plane_ >> 3) & 1) << 4;                           \
        const size_t g_  = pb_ + (size_t)plane_ * HWSZ                         \
                         + (size_t)(((lane & 31) * 4) ^ sw_);                  \
        __builtin_amdgcn_global_load_lds(                                      \
            (const __attribute__((address_space(1))) unsigned int*)(x + g_),   \
            (__attribute__((address_space(3))) unsigned int*)&lx[BSEL][row_][0],\
            16, 0, 0);                                                         \
    }                                                                          \
} while (0)

// Compute tile T from lx[BSEL]. Wave wv owns pts [wv*32, wv*32+32) = 2 subs.
// A: lane holds A[row=pt=ln][k=lg*8+e] built from swizzled ds_reads; 4 MFMA
// per m (2 kk x {hi,lo}); D: lane,reg r -> [pt=lg*4+r][j=ln] => float4 store.
#define COMPUTE(BSEL, T) do {                                                  \
    const size_t po_ = TILE_PB(T);                                             \
    _Pragma("unroll")                                                          \
    for (int sub_ = 0; sub_ < 2; ++sub_) {                                     \
        const int pt_ = wv * 32 + sub_ * 16 + ln;                              \
        fragU ah_[2], al_[2];                                                  \
        _Pragma("unroll")                                                      \
        for (int kk_ = 0; kk_ < 2; ++kk_) {                                    \
            _Pragma("unroll")                                                  \
            for (int w_ = 0; w_ < 4; ++w_) {                                   \
                const int i0_ = kk_ * 32 + lg * 8 + 2 * w_;                    \
                const float v0_ = lx[BSEL][i0_][pt_ ^ (((i0_ >> 3) & 1) << 4)];\
                const float v1_ = lx[BSEL][i0_ + 1]                            \
                                    [pt_ ^ ((((i0_ + 1) >> 3) & 1) << 4)];     \
                const float a0_ = __logf(fmaxf(v0_, 0.0f) + 0.1f);             \
                const float a1_ = __logf(fmaxf(v1_, 0.0f) + 0.1f);             \
                ah_[kk_].u[w_] = (fbits(a1_) & 0xFFFF0000u) | (fbits(a0_) >> 16); \
                const float b0_ = a0_ - bfup(fbits(a0_));                      \
                const float b1_ = a1_ - bfup(fbits(a1_));                      \
                al_[kk_].u[w_] = (fbits(b1_) & 0xFFFF0000u) | (fbits(b0_) >> 16); \
            }                                                                  \
        }                                                                      \
        _Pragma("unroll")                                                      \
        for (int m_ = 0; m_ < 4; ++m_) {                                       \
            f32x4 acc_ = {0.f, 0.f, 0.f, 0.f};                                 \
            _Pragma("unroll")                                                  \
            for (int kk_ = 0; kk_ < 2; ++kk_) {                                \
                acc_ = __builtin_amdgcn_mfma_f32_16x16x32_bf16(                \
                           ah_[kk_].v, bE[m_][kk_], acc_, 0, 0, 0);            \
                acc_ = __builtin_amdgcn_mfma_f32_16x16x32_bf16(                \
                           al_[kk_].v, bE[m_][kk_], acc_, 0, 0, 0);            \
            }                                                                  \
            float4 o_;                                                         \
            o_.x = __expf(acc_[0]) + bj[m_];                                   \
            o_.y = __expf(acc_[1]) + bj[m_];                                   \
            o_.z = __expf(acc_[2]) + bj[m_];                                   \
            o_.w = __expf(acc_[3]) + bj[m_];                                   \
            *reinterpret_cast<float4*>(out + po_                               \
                + (size_t)(m_ * 16 + ln) * HWSZ                                \
                + (size_t)(wv * 32 + sub_ * 16 + lg * 4)) = o_;                \
        }                                                                      \
    }                                                                          \
} while (0)

    // ---- dbuf pipeline: stage t+1 | wait(counted) | barrier | compute t ----
    STAGE(0, (int)blockIdx.x);
    #pragma unroll
    for (int t = 0; t < TPB; ++t) {
        if (t + 1 < TPB) STAGE((t + 1) & 1, (int)blockIdx.x + (t + 1) * NBLOCKS);
        // wait for THIS tile's 8 staging loads; in-order vmem retirement:
        // younger = 8 prev-compute stores + 8 just-issued stage (16), or 8
        // at the pipeline ends. Never vmcnt(0): next stage stays in flight.
        if (t == 0 || t == TPB - 1) {
            asm volatile("s_waitcnt vmcnt(8)" ::: "memory");
        } else {
            asm volatile("s_waitcnt vmcnt(16)" ::: "memory");
        }
        __builtin_amdgcn_s_barrier();          // all waves' staging visible
        __builtin_amdgcn_sched_barrier(0);     // no ds_read hoists above
        COMPUTE(t & 1, (int)blockIdx.x + t * NBLOCKS);
        if (t + 1 < TPB) {
            __builtin_amdgcn_s_barrier();      // reads done before buf reuse
            __builtin_amdgcn_sched_barrier(0);
        }
    }

#undef TILE_PB
#undef STAGE
#undef COMPUTE
}

extern "C" void kernel_launch(void* const* d_in, const int* in_sizes, int n_in,
                              void* d_out, int out_size, void* d_ws, size_t ws_size,
                              hipStream_t stream) {
    const float* x    = (const float*)d_in[0];
    const float* E    = (const float*)d_in[1];   // (64,64,1,1) -> [i*64+j]
    const float* bias = (const float*)d_in[2];   // (64,1,1)
    float* out = (float*)d_out;

    dim3 grid(NBLOCKS), block(256);
    hipLaunchKernelGGL(fused_log_einsum_exp, grid, block, 0, stream,
                       x, E, bias, out);
}